// Round 11
// baseline (132.775 us; speedup 1.0000x reference)
//
#include <hip/hip_runtime.h>
#include <math.h>

// SO3 convolution lmax=2 — memset + prep(bucket+cgsort) + chunk4 + reduce4.
//   K0) hipMemsetAsync(cnt) — tiny.
//   K1) prep_kernel: buckets edges by destination atom (1 atomic + 1 store
//       per edge); last block counting-sorts the ~150 sparse-CG entries by
//       output cell (cell = i3*9+i1, 81 cells) -> cellOff/cellDat.
//   K2) so3_chunk_kernel: 256 thr = 4 INDEPENDENT chunk-waves per block
//       (key change vs R10: 1-wave blocks only reached ~2.5 workgroups/CU
//       resident; 4-wave blocks pack ~4x the waves -> latency overlap).
//       cg tables loaded once per block (single barrier), then each wave:
//       chunk of CEDGE=8 edges in a PRIVATE LDS section — metadata+Y,
//       radial->LDS, B1 one shared Wf pass -> w[8][3] regs, M-build
//       per-cell in REGISTERS (no atomics, no zero-init), 8-edge
//       gather+contract, plain slot store. Last chunk loops for deg>24.
//   K3) reduce_kernel: 4 atoms per block (wave per atom) sums slots -> out.
//   No global atomics. Fallback (ws small / ncg > MAXCG): R8 fused kernel.

#define S9     9
#define MROW   12
#define MSZ    (S9 * MROW)      // 108
#define NF     128
#define NRAD   20
#define CEDGE  8
#define NCHUNK 3                // covers deg <= 24 in distinct chunks
#define CAP    64
#define NCELL  81
#define MAXCG  512

__device__ inline float2 f2fma(float a, float2 b, float2 c) {
    return make_float2(fmaf(a, b.x, c.x), fmaf(a, b.y, c.y));
}

// ---------- K1: bucket scatter + cg cell-sort ----------
__global__ __launch_bounds__(256) void prep_kernel(
    const int* __restrict__ idx_i, int E, int nbuck,
    const int* __restrict__ cg_i1, const int* __restrict__ cg_i2,
    const int* __restrict__ cg_i3, const float* __restrict__ cg_vals, int ncg,
    int* __restrict__ cnt,          // [A], pre-zeroed
    int* __restrict__ buck,         // [A*CAP]
    int* __restrict__ cellOff,      // [NCELL+1]
    int2* __restrict__ cellDat)     // [ncg] (s2, bits(val)) grouped by cell
{
    const int t = threadIdx.x;
    if ((int)blockIdx.x < nbuck) {
        int e = blockIdx.x * 256 + t;
        if (e < E) {
            int a = idx_i[e];
            int p = atomicAdd(&cnt[a], 1);
            if (p < CAP) buck[a * CAP + p] = e;
        }
        return;
    }
    __shared__ int hist[NCELL];
    __shared__ int cur[NCELL];
    if (t < NCELL) hist[t] = 0;
    __syncthreads();
    for (int k = t; k < ncg; k += 256)
        atomicAdd(&hist[cg_i3[k] * S9 + cg_i1[k]], 1);
    __syncthreads();
    if (t == 0) {
        int run = 0;
        for (int c = 0; c < NCELL; ++c) {
            cellOff[c] = run; cur[c] = run; run += hist[c];
        }
        cellOff[NCELL] = run;
    }
    __syncthreads();
    for (int k = t; k < ncg; k += 256) {
        int cell = cg_i3[k] * S9 + cg_i1[k];
        int p = atomicAdd(&cur[cell], 1);
        cellDat[p] = make_int2(cg_i2[k], __float_as_int(cg_vals[k]));
    }
}

// ---------- K2: 4 independent chunk-waves per block ----------
__global__ __launch_bounds__(256) void so3_chunk_kernel(
    const float* __restrict__ x,        // [A, 9, 128]
    const float* __restrict__ radial,   // [E, 20]
    const float* __restrict__ dir,      // [E, 3]
    const float* __restrict__ cutoff,   // [E]
    const float* __restrict__ Wf,       // [20, 384]
    const float* __restrict__ bf,       // [384]
    const int* __restrict__ idx_j,
    const int* __restrict__ cnt,        // [A]
    const int* __restrict__ buck,       // [A*CAP]
    const int* __restrict__ cellOff,    // [NCELL+1]
    const int2* __restrict__ cellDat,   // [ncg]
    int ncg, int A,
    float* __restrict__ slots)          // [A*NCHUNK, 9, 128]
{
    const int t    = threadIdx.x;
    const int lane = t & 63;             // f-pair index
    const int wid  = t >> 6;
    const int ch   = blockIdx.x * 4 + wid;

    __shared__ __align__(16) float M[4][CEDGE][MSZ];    // 13824 B
    __shared__ float Ysh[4][CEDGE][S9];
    __shared__ float radsh[4][CEDGE][NRAD];
    __shared__ float cutsh[4][CEDGE];
    __shared__ int   egsh[4][CEDGE];
    __shared__ int   jsh[4][CEDGE];
    __shared__ int   offsh[NCELL + 1];
    __shared__ int2  datsh[MAXCG];

    // active-chunk determination (issues cnt load early)
    int a = 0, q = 0, deg = 0;
    bool active = (ch < A * NCHUNK);
    if (active) {
        a = ch / NCHUNK;
        q = ch - a * NCHUNK;
        deg = min(cnt[a], CAP);
        if (q > 0 && q * CEDGE >= deg) active = false;
    }

    // cg tables: loaded ONCE per block, shared by all 4 waves
    for (int k = t; k <= NCELL; k += 256) offsh[k] = cellOff[k];
    for (int k = t; k < ncg; k += 256) datsh[k] = cellDat[k];
    __syncthreads();                    // the only barrier in this kernel
    if (!active) return;

    float2 acc[S9];
    #pragma unroll
    for (int s = 0; s < S9; ++s) acc[s] = make_float2(0.f, 0.f);

    const float2 b0 = ((const float2*)(bf + 0 * NF))[lane];
    const float2 b1 = ((const float2*)(bf + 1 * NF))[lane];
    const float2 b2 = ((const float2*)(bf + 2 * NF))[lane];

    int base = q * CEDGE;
    do {
        const int n = min(CEDGE, deg - base);

        // ---- metadata + Y (lanes 0-7; tails exact-zero) ----
        if (lane < CEDGE) {
            int e = 0, jj = a;
            float cut = 0.f;
            float y0 = 0.f, y1 = 0.f, y2 = 0.f, y3 = 0.f, y4 = 0.f,
                  y5 = 0.f, y6 = 0.f, y7 = 0.f, y8 = 0.f;
            if (lane < n) {
                e = buck[a * CAP + base + lane];
                jj = idx_j[e];
                cut = cutoff[e];
                float dx = dir[3 * e], dy = dir[3 * e + 1], dz = dir[3 * e + 2];
                const float inv = rsqrtf(dx * dx + dy * dy + dz * dz);
                dx *= inv; dy *= inv; dz *= inv;
                const float s3c  = 1.7320508075688772f;
                const float s5c  = 2.2360679774997896f;
                const float s15c = 3.8729833462074170f;
                y0 = 1.0f;
                y1 = s3c * dy; y2 = s3c * dz; y3 = s3c * dx;
                y4 = s15c * dx * dy; y5 = s15c * dy * dz;
                y6 = 0.5f * s5c * (3.0f * dz * dz - 1.0f);
                y7 = s15c * dx * dz;
                y8 = 0.5f * s15c * (dx * dx - dy * dy);
            }
            egsh[wid][lane] = e; jsh[wid][lane] = jj; cutsh[wid][lane] = cut;
            Ysh[wid][lane][0] = y0; Ysh[wid][lane][1] = y1; Ysh[wid][lane][2] = y2;
            Ysh[wid][lane][3] = y3; Ysh[wid][lane][4] = y4; Ysh[wid][lane][5] = y5;
            Ysh[wid][lane][6] = y6; Ysh[wid][lane][7] = y7; Ysh[wid][lane][8] = y8;
        }
        // ---- radial -> LDS (tails zero); same-wave DS ordering, no barrier ----
        for (int qq = lane; qq < CEDGE * NRAD; qq += 64) {
            const int c = qq / NRAD;
            const int r = qq - c * NRAD;
            float v = 0.f;
            if (c < n) v = radial[(size_t)egsh[wid][c] * NRAD + r];
            radsh[wid][c][r] = v;
        }

        // ---- B1: one Wf pass for all 8 slots -> registers ----
        float2 w[CEDGE][3];
        #pragma unroll
        for (int c = 0; c < CEDGE; ++c) { w[c][0] = b0; w[c][1] = b1; w[c][2] = b2; }
        #pragma unroll 4
        for (int r = 0; r < NRAD; ++r) {
            const float2* wrow = (const float2*)(Wf + r * (3 * NF));
            const float2 w0 = wrow[lane];
            const float2 w1 = wrow[lane + 64];
            const float2 w2 = wrow[lane + 128];
            #pragma unroll
            for (int c = 0; c < CEDGE; ++c) {
                const float rv = radsh[wid][c][r];   // 0 for tails
                w[c][0] = f2fma(rv, w0, w[c][0]);
                w[c][1] = f2fma(rv, w1, w[c][1]);
                w[c][2] = f2fma(rv, w2, w[c][2]);
            }
        }
        #pragma unroll
        for (int c = 0; c < CEDGE; ++c) {
            const float cut = cutsh[wid][c];         // 0 for tails -> w = 0
            w[c][0].x *= cut; w[c][0].y *= cut;
            w[c][1].x *= cut; w[c][1].y *= cut;
            w[c][2].x *= cut; w[c][2].y *= cut;
        }

        // ---- M-build: per-cell register FMA, no atomics, no zero-init ----
        #pragma unroll
        for (int cc = 0; cc < 2; ++cc) {
            const int cell = lane + cc * 64;
            if (cell < NCELL) {
                const int s3i = cell / 9;
                const int s1i = cell - 9 * s3i;
                const int o0 = offsh[cell], o1 = offsh[cell + 1];
                float m[CEDGE];
                #pragma unroll
                for (int c = 0; c < CEDGE; ++c) m[c] = 0.f;
                for (int idx = o0; idx < o1; ++idx) {
                    const int2 d = datsh[idx];
                    const float v = __int_as_float(d.y);
                    #pragma unroll
                    for (int c = 0; c < CEDGE; ++c)
                        m[c] = fmaf(v, Ysh[wid][c][d.x], m[c]);
                }
                #pragma unroll
                for (int c = 0; c < CEDGE; ++c) M[wid][c][s3i * MROW + s1i] = m[c];
            }
        }

        // ---- gather + contract (tails: M=0 and w=0 -> exact zeros) ----
        #pragma unroll
        for (int c = 0; c < CEDGE; ++c) {
            const int j = __builtin_amdgcn_readfirstlane(jsh[wid][c]);
            const float2* xp = (const float2*)(x + (size_t)j * (S9 * NF)) + lane;
            float2 xj[S9];
            #pragma unroll
            for (int s = 0; s < S9; ++s) xj[s] = xp[s * 64];

            #pragma unroll
            for (int s3 = 0; s3 < S9; ++s3) {
                const float4* mr = (const float4*)&M[wid][c][s3 * MROW];
                const float4 m0 = mr[0];
                const float4 m1 = mr[1];
                const float  m8 = M[wid][c][s3 * MROW + 8];
                float2 tsum = make_float2(0.f, 0.f);
                tsum = f2fma(m0.x, xj[0], tsum);
                tsum = f2fma(m0.y, xj[1], tsum);
                tsum = f2fma(m0.z, xj[2], tsum);
                tsum = f2fma(m0.w, xj[3], tsum);
                tsum = f2fma(m1.x, xj[4], tsum);
                tsum = f2fma(m1.y, xj[5], tsum);
                tsum = f2fma(m1.z, xj[6], tsum);
                tsum = f2fma(m1.w, xj[7], tsum);
                tsum = f2fma(m8,   xj[8], tsum);
                const float2 wl = (s3 == 0) ? w[c][0] : ((s3 < 4) ? w[c][1] : w[c][2]);
                acc[s3].x = fmaf(wl.x, tsum.x, acc[s3].x);
                acc[s3].y = fmaf(wl.y, tsum.y, acc[s3].y);
            }
        }
        base += CEDGE;
    } while (q == NCHUNK - 1 && base < deg);   // overflow loop (deg > 24)

    // ---- slot store (plain) ----
    float2* sp = (float2*)(slots + (size_t)(a * NCHUNK + q) * (S9 * NF)) + lane;
    #pragma unroll
    for (int s = 0; s < S9; ++s) sp[s * 64] = acc[s];
}

// ---------- K3: 4 atoms per block, wave per atom ----------
__global__ __launch_bounds__(256) void reduce_kernel(
    const float* __restrict__ slots, const int* __restrict__ cnt, int A,
    float* __restrict__ out)
{
    const int a = blockIdx.x * 4 + (threadIdx.x >> 6);
    if (a >= A) return;
    const int t = threadIdx.x & 63;
    const int deg = min(cnt[a], CAP);
    const int nch = min((deg + CEDGE - 1) / CEDGE, NCHUNK);

    float2 acc[S9];
    #pragma unroll
    for (int s = 0; s < S9; ++s) acc[s] = make_float2(0.f, 0.f);

    for (int q = 0; q < nch; ++q) {
        const float2* sp = (const float2*)(slots + (size_t)(a * NCHUNK + q) * (S9 * NF)) + t;
        #pragma unroll
        for (int s = 0; s < S9; ++s) {
            float2 v = sp[s * 64];
            acc[s].x += v.x; acc[s].y += v.y;
        }
    }
    float2* op = (float2*)(out + (size_t)a * (S9 * NF)) + t;
    #pragma unroll
    for (int s = 0; s < S9; ++s) op[s * 64] = acc[s];
}

// ---------- fallback: R8 fused edge kernel with global atomics ----------
__global__ __launch_bounds__(256) void so3_edge_fused(
    const float* __restrict__ x, const float* __restrict__ radial,
    const float* __restrict__ dir, const float* __restrict__ cutoff,
    const float* __restrict__ Wf, const float* __restrict__ bf,
    const float* __restrict__ cg_vals,
    const int* __restrict__ idx_i, const int* __restrict__ idx_j,
    const int* __restrict__ cg_i1, const int* __restrict__ cg_i2,
    const int* __restrict__ cg_i3, int ncg, int E,
    float* __restrict__ out)
{
    const int wid  = threadIdx.x >> 6;
    const int lane = threadIdx.x & 63;
    const int e = blockIdx.x * 4 + wid;
    if (e >= E) return;

    __shared__ __align__(16) float Msh[4][MSZ];
    __shared__ float Ysh[4][S9];

    if (lane < 27) ((float4*)&Msh[wid][0])[lane] = make_float4(0.f, 0.f, 0.f, 0.f);

    float dx = dir[3 * e], dy = dir[3 * e + 1], dz = dir[3 * e + 2];
    const float inv = rsqrtf(dx * dx + dy * dy + dz * dz);
    dx *= inv; dy *= inv; dz *= inv;
    if (lane == 0) {
        const float s3c = 1.7320508075688772f, s5c = 2.2360679774997896f,
                    s15c = 3.8729833462074170f;
        Ysh[wid][0] = 1.0f;
        Ysh[wid][1] = s3c * dy; Ysh[wid][2] = s3c * dz; Ysh[wid][3] = s3c * dx;
        Ysh[wid][4] = s15c * dx * dy; Ysh[wid][5] = s15c * dy * dz;
        Ysh[wid][6] = 0.5f * s5c * (3.0f * dz * dz - 1.0f);
        Ysh[wid][7] = s15c * dx * dz;
        Ysh[wid][8] = 0.5f * s15c * (dx * dx - dy * dy);
    }
    for (int k = lane; k < ncg; k += 64)
        atomicAdd(&Msh[wid][cg_i3[k] * MROW + cg_i1[k]], cg_vals[k] * Ysh[wid][cg_i2[k]]);

    float rad[NRAD];
    #pragma unroll
    for (int r = 0; r < NRAD; ++r) rad[r] = radial[(size_t)e * NRAD + r];
    const float cut = cutoff[e];

    float2 w0 = ((const float2*)(bf + 0 * NF))[lane];
    float2 w1 = ((const float2*)(bf + 1 * NF))[lane];
    float2 w2 = ((const float2*)(bf + 2 * NF))[lane];
    #pragma unroll 4
    for (int r = 0; r < NRAD; ++r) {
        const float2* wrow = (const float2*)(Wf + r * (3 * NF));
        w0 = f2fma(rad[r], wrow[lane], w0);
        w1 = f2fma(rad[r], wrow[lane + 64], w1);
        w2 = f2fma(rad[r], wrow[lane + 128], w2);
    }
    w0.x *= cut; w0.y *= cut; w1.x *= cut; w1.y *= cut; w2.x *= cut; w2.y *= cut;

    const int j = __builtin_amdgcn_readfirstlane(idx_j[e]);
    const float2* xp = (const float2*)(x + (size_t)j * (S9 * NF)) + lane;
    float2 xj[S9];
    #pragma unroll
    for (int s = 0; s < S9; ++s) xj[s] = xp[s * 64];

    const int a = __builtin_amdgcn_readfirstlane(idx_i[e]);
    float* op = out + (size_t)a * (S9 * NF) + 2 * lane;
    #pragma unroll
    for (int s3 = 0; s3 < S9; ++s3) {
        const float4* mr = (const float4*)&Msh[wid][s3 * MROW];
        const float4 m0 = mr[0];
        const float4 m1 = mr[1];
        const float  m8 = Msh[wid][s3 * MROW + 8];
        float2 tsum = make_float2(0.f, 0.f);
        tsum = f2fma(m0.x, xj[0], tsum);
        tsum = f2fma(m0.y, xj[1], tsum);
        tsum = f2fma(m0.z, xj[2], tsum);
        tsum = f2fma(m0.w, xj[3], tsum);
        tsum = f2fma(m1.x, xj[4], tsum);
        tsum = f2fma(m1.y, xj[5], tsum);
        tsum = f2fma(m1.z, xj[6], tsum);
        tsum = f2fma(m1.w, xj[7], tsum);
        tsum = f2fma(m8,   xj[8], tsum);
        const float2 wl = (s3 == 0) ? w0 : ((s3 < 4) ? w1 : w2);
        atomicAdd(&op[s3 * NF],     wl.x * tsum.x);
        atomicAdd(&op[s3 * NF + 1], wl.y * tsum.y);
    }
}

extern "C" void kernel_launch(void* const* d_in, const int* in_sizes, int n_in,
                              void* d_out, int out_size, void* d_ws, size_t ws_size,
                              hipStream_t stream) {
    const float* x       = (const float*)d_in[0];
    const float* radial  = (const float*)d_in[1];
    const float* dir     = (const float*)d_in[2];
    const float* cutoff  = (const float*)d_in[3];
    const float* Wf      = (const float*)d_in[4];
    const float* bf      = (const float*)d_in[5];
    const float* cg_vals = (const float*)d_in[6];
    const int*   idx_i   = (const int*)d_in[7];
    const int*   idx_j   = (const int*)d_in[8];
    const int*   cg_i1   = (const int*)d_in[9];
    const int*   cg_i2   = (const int*)d_in[10];
    const int*   cg_i3   = (const int*)d_in[11];
    // d_in[12] = w_idx: unused (folded into kernel)

    const int E   = in_sizes[7];
    const int ncg = in_sizes[6];
    const int A   = in_sizes[0] / (S9 * NF);

    // ws: cnt[A] | cellOff[82] | buck[A*CAP] | (align) | cellDat[ncg] | (align) | slots
    int* cnt      = (int*)d_ws;
    int* cellOff  = cnt + A;
    int* buck     = cellOff + (NCELL + 1);
    size_t ib     = (size_t)(A + NCELL + 1 + A * CAP) * sizeof(int);
    size_t doff   = (ib + 255) & ~(size_t)255;
    int2* cellDat = (int2*)((char*)d_ws + doff);
    size_t soff   = (doff + (size_t)ncg * sizeof(int2) + 255) & ~(size_t)255;
    float* slots  = (float*)((char*)d_ws + soff);
    size_t need   = soff + (size_t)A * NCHUNK * (S9 * NF) * sizeof(float);

    if (ws_size >= need && ncg <= MAXCG) {
        hipMemsetAsync(cnt, 0, (size_t)A * sizeof(int), stream);

        const int nbuck = (E + 255) / 256;
        prep_kernel<<<nbuck + 1, 256, 0, stream>>>(
            idx_i, E, nbuck, cg_i1, cg_i2, cg_i3, cg_vals, ncg,
            cnt, buck, cellOff, cellDat);

        const int nch_total = A * NCHUNK;
        so3_chunk_kernel<<<(nch_total + 3) / 4, 256, 0, stream>>>(
            x, radial, dir, cutoff, Wf, bf, idx_j,
            cnt, buck, cellOff, cellDat, ncg, A, slots);

        reduce_kernel<<<(A + 3) / 4, 256, 0, stream>>>(slots, cnt, A, (float*)d_out);
    } else {
        hipMemsetAsync(d_out, 0, (size_t)out_size * sizeof(float), stream);
        so3_edge_fused<<<(E + 3) / 4, 256, 0, stream>>>(
            x, radial, dir, cutoff, Wf, bf, cg_vals, idx_i, idx_j,
            cg_i1, cg_i2, cg_i3, ncg, E, (float*)d_out);
    }
}